// Round 6
// baseline (1349.265 us; speedup 1.0000x reference)
//
#include <hip/hip_runtime.h>

#define B_    32
#define N_    64
#define IN_   2048
#define D_    32
#define K_    16
#define BH    8                    /* batches per block */
#define NBG   (B_/BH)              /* 4 batch groups */
#define ITILE 16
#define NTILE (IN_/ITILE)          /* 128 i-tiles */
#define NBLK  (NTILE*NBG)          /* 512 blocks */
#define PCELLS ((size_t)BH*N_*D_)  /* 16384 */
#define CELLS  ((size_t)B_*N_*D_)  /* 65536 */

// softmax_e(v * INV_LOG2) == 2^((v-max) * (1/ln2)^2)
#define SM_SCALE 2.0813689810056077f

// -----------------------------------------------------------------------------
// route_kernel: one pass over W. 256-thread block = (i-tile, batch-group of 8).
// R5 lesson: 256-thr blocks get honest register allocation (no 64-VGPR spill).
// This round: BH=8 halves duplicate W reads (NBG 8->4: 2 GB -> 1 GB L2/pass),
// uh[8][8] lives in REGISTERS across the softmax barrier (no LDS round-trip),
// k4-outer ordering keeps W loads at the 32/i minimum with x scalar-loaded
// (wave-uniform addresses -> SGPRs, proven R5). ~160 VGPRs of live state gives
// the scheduler a deep VMEM window (R5's 36-VGPR kernel was latency-bound,
// VALUBusy 17.7%).
// -----------------------------------------------------------------------------
template<bool FIRST>
__global__ __launch_bounds__(256, 1)
void route_kernel(const float* __restrict__ x, const float* __restrict__ W,
                  const float* __restrict__ os, float* __restrict__ part)
{
    __shared__ float logit_s[BH][N_];    // 2 KB

    const int tid  = threadIdx.x;   // 0..255
    const int w    = tid >> 6;      // wave 0..3
    const int l    = tid & 63;
    const int d    = l & 31;        // output dim this thread owns
    const int hi   = l >> 5;
    const int slot = w * 2 + hi;    // 0..7 -> n = r*8 + slot

    // 4 same-tile batch-group blocks consecutive on one XCD (bid%8 = XCD)
    const int virt = (blockIdx.x & 7) * (NBLK / 8) + (blockIdx.x >> 3);
    const int tile = virt / NBG;
    const int bg   = virt % NBG;
    const int b0   = bg * BH;
    const int i0   = tile * ITILE;

    float s_acc[8][BH];             // 64 VGPRs
    #pragma unroll
    for (int r = 0; r < 8; ++r)
        #pragma unroll
        for (int jb = 0; jb < BH; ++jb) s_acc[r][jb] = 0.f;

    for (int ii = 0; ii < ITILE; ++ii) {
        const int i = i0 + ii;
        const float* xb = x + (size_t)b0 * (IN_ * K_) + (size_t)i * K_;
        const float* wb = W + (((size_t)slot * IN_ + i) * D_ + d) * K_;

        float uh[8][BH];            // 64 VGPRs, live across softmax (!FIRST)
        if (!FIRST) {
            #pragma unroll
            for (int r = 0; r < 8; ++r)
                #pragma unroll
                for (int jb = 0; jb < BH; ++jb) uh[r][jb] = 0.f;
        }

        #pragma unroll
        for (int k4 = 0; k4 < 4; ++k4) {
            // x chunk: wave-uniform addresses -> scalar loads (SGPRs)
            float4 xr[BH];
            #pragma unroll
            for (int jb = 0; jb < BH; ++jb)
                xr[jb] = *(const float4*)(xb + (size_t)jb * (IN_ * K_) + k4 * 4);
            // W: one float4 per (r, k4) -- the 32/i minimum
            #pragma unroll
            for (int r = 0; r < 8; ++r) {
                const float4 wv = *(const float4*)(wb + (size_t)r * (8ull * IN_ * D_ * K_) + k4 * 4);
                #pragma unroll
                for (int jb = 0; jb < BH; ++jb) {
                    const float acc = wv.x * xr[jb].x + wv.y * xr[jb].y
                                    + wv.z * xr[jb].z + wv.w * xr[jb].w;
                    if (FIRST) s_acc[r][jb] += acc;   // c uniform: no uh needed
                    else       uh[r][jb]   += acc;
                }
            }
        }

        if (!FIRST) {
            // logits[b][n] = sum_d uh*os -- butterfly over the 32 d-lanes
            #pragma unroll
            for (int r = 0; r < 8; ++r) {
                const int n = r * 8 + slot;
                #pragma unroll
                for (int jb = 0; jb < BH; ++jb) {
                    float t = uh[r][jb] * os[((size_t)(b0 + jb) * N_ + n) * D_ + d];
                    #pragma unroll
                    for (int m = 1; m < 32; m <<= 1) t += __shfl_xor(t, m, 64);
                    if (d == 0) logit_s[jb][n] = t;   // lanes 0 & 32
                }
            }
            __syncthreads();
            // softmax over n: each wave handles 2 batches, 64 lanes = n
            #pragma unroll
            for (int s = 0; s < 2; ++s) {
                const int jb = w * 2 + s;
                const float v = logit_s[jb][l];
                float mx = v;
                #pragma unroll
                for (int m = 1; m < 64; m <<= 1) mx = fmaxf(mx, __shfl_xor(mx, m, 64));
                const float e = exp2f((v - mx) * SM_SCALE);
                float sum = e;
                #pragma unroll
                for (int m = 1; m < 64; m <<= 1) sum += __shfl_xor(sum, m, 64);
                logit_s[jb][l] = e / sum;
            }
            __syncthreads();
            // weighted accumulate straight from registers
            #pragma unroll
            for (int r = 0; r < 8; ++r) {
                const int n = r * 8 + slot;
                #pragma unroll
                for (int jb = 0; jb < BH; ++jb)
                    s_acc[r][jb] += logit_s[jb][n] * uh[r][jb];
            }
            __syncthreads();   // protect logit_s before next i's partial writes
        }
    }

    const float scale = FIRST ? (1.0f / 64.0f) : 1.0f;
    float* myp = part + (size_t)virt * PCELLS;
    #pragma unroll
    for (int r = 0; r < 8; ++r) {
        const int n = r * 8 + slot;
        #pragma unroll
        for (int jb = 0; jb < BH; ++jb)
            myp[((size_t)jb * N_ + n) * D_ + d] = s_acc[r][jb] * scale;
    }
}

// -----------------------------------------------------------------------------
// finish_kernel: s = sum of partials; out = squash(s);
// FINAL=false: os += out (next pass's logit operand); FINAL=true: write d_out.
// Partial layout: part[tile*NBG+bg][jb][n][d], b = bg*BH+jb.
// -----------------------------------------------------------------------------
template<bool FINAL>
__global__ __launch_bounds__(256)
void finish_kernel(const float* __restrict__ part,
                   float* __restrict__ os, float* __restrict__ out)
{
    const int gid = blockIdx.x * 256 + threadIdx.x;   // 0..65535
    const int b   = gid >> 11;        // 0..31
    const int rem = gid & 2047;       // n*32+d
    const int bg = b >> 3, jb = b & 7;
    const float* p0 = part + (size_t)bg * PCELLS + (size_t)jb * (N_ * D_) + rem;
    float v = 0.f;
    for (int t = 0; t < NTILE; ++t) v += p0[(size_t)t * NBG * PCELLS];

    float sq = v * v;
    #pragma unroll
    for (int m = 1; m < 32; m <<= 1) sq += __shfl_xor(sq, m, 64);  // sum over d
    const float scale = sqrtf(sq) / (1.0f + sq);
    const float o = v * scale;
    if (FINAL) out[gid] = o;
    else       os[gid] += o;
}

extern "C" void kernel_launch(void* const* d_in, const int* in_sizes, int n_in,
                              void* d_out, int out_size, void* d_ws, size_t ws_size,
                              hipStream_t stream)
{
    const float* x = (const float*)d_in[0];
    const float* W = (const float*)d_in[1];
    float* out = (float*)d_out;

    // ws: [NBLK][PCELLS] partials (32 MB, proven to fit in R5) + out_sum
    float* part = (float*)d_ws;
    float* os   = part + (size_t)NBLK * PCELLS;

    hipMemsetAsync(os, 0, CELLS * 4, stream);

    for (int it = 0; it < 3; ++it) {
        if (it == 0) route_kernel<true ><<<NBLK, 256, 0, stream>>>(x, W, os, part);
        else         route_kernel<false><<<NBLK, 256, 0, stream>>>(x, W, os, part);
        if (it < 2)  finish_kernel<false><<<CELLS / 256, 256, 0, stream>>>(part, os, nullptr);
        else         finish_kernel<true ><<<CELLS / 256, 256, 0, stream>>>(part, nullptr, out);
    }
}

// Round 7
// 918.935 us; speedup vs baseline: 1.4683x; 1.4683x over previous
//
#include <hip/hip_runtime.h>

#define B_    32
#define N_    64
#define IN_   2048
#define D_    32
#define K_    16
#define BH    4                    /* batches per block */
#define NBG   (B_/BH)              /* 8 batch groups */
#define ITILE 8
#define NTILE (IN_/ITILE)          /* 256 i-tiles */
#define NBLK  (NTILE*NBG)          /* 2048 blocks */
#define PCELLS ((size_t)BH*N_*D_)  /* 8192 */
#define CELLS  ((size_t)B_*N_*D_)  /* 65536 */

// softmax_e(v * INV_LOG2) == 2^((v-max) * (1/ln2)^2)
#define SM_SCALE 2.0813689810056077f

// -----------------------------------------------------------------------------
// route_kernel: one pass over W. 256-thread block = (i-tile of 8, batch-group
// of 4). R5 (244us) was latency-bound: occupancy 39% (LDS-capped: 32KB uh_s ->
// 4 blocks/CU), VALUBusy 17.7%, L2 at 24% of peak. R6 proved big register
// state + small grid makes it worse. This round: uh[8][4] stays in REGISTERS
// (only 32 VGPRs, kills the 32KB LDS buffer -> LDS 1KB), grid doubled to 2048
// blocks -> target 5-6 blocks/CU, 20-24 waves/CU of latency hiding.
// -----------------------------------------------------------------------------
template<bool FIRST>
__global__ __launch_bounds__(256, 1)
void route_kernel(const float* __restrict__ x, const float* __restrict__ W,
                  const float* __restrict__ os, float* __restrict__ part, int P)
{
    __shared__ float logit_s[BH][N_];    // 1 KB, single-buffered (3 syncs/i)

    const int tid  = threadIdx.x;   // 0..255
    const int w    = tid >> 6;      // wave 0..3
    const int l    = tid & 63;
    const int d    = l & 31;        // output dim this thread owns
    const int hi   = l >> 5;
    const int slot = w * 2 + hi;    // 0..7 -> n = r*8 + slot

    // same-tile batch-group blocks consecutive on one XCD (bid%8 = XCD)
    const int virt = (blockIdx.x & 7) * (NBLK / 8) + (blockIdx.x >> 3);
    const int tile = virt / NBG;
    const int bg   = virt % NBG;
    const int b0   = bg * BH;
    const int i0   = tile * ITILE;

    float s_acc[8][BH];             // 32 VGPRs
    #pragma unroll
    for (int r = 0; r < 8; ++r)
        #pragma unroll
        for (int jb = 0; jb < BH; ++jb) s_acc[r][jb] = 0.f;

    for (int ii = 0; ii < ITILE; ++ii) {
        const int i = i0 + ii;
        const float* xb = x + (size_t)b0 * (IN_ * K_) + (size_t)i * K_;
        const float* wb = W + (((size_t)slot * IN_ + i) * D_ + d) * K_;

        if (FIRST) {
            // c uniform (1/64, folded at store): accumulate dots directly
            #pragma unroll
            for (int r = 0; r < 8; ++r) {
                const float* wr = wb + (size_t)r * (8ull * IN_ * D_ * K_);
                #pragma unroll
                for (int k4 = 0; k4 < 4; ++k4) {
                    const float4 wv = ((const float4*)wr)[k4];
                    #pragma unroll
                    for (int jb = 0; jb < BH; ++jb) {
                        // wave-uniform address -> scalar load (SGPR, proven R5)
                        const float4 xv = *(const float4*)(xb + (size_t)jb * (IN_ * K_) + k4 * 4);
                        s_acc[r][jb] += wv.x*xv.x + wv.y*xv.y + wv.z*xv.z + wv.w*xv.w;
                    }
                }
            }
        } else {
            float uh[8][BH];        // 32 VGPRs, live across softmax
            #pragma unroll
            for (int r = 0; r < 8; ++r)
                #pragma unroll
                for (int jb = 0; jb < BH; ++jb) uh[r][jb] = 0.f;

            #pragma unroll
            for (int r = 0; r < 8; ++r) {
                const float* wr = wb + (size_t)r * (8ull * IN_ * D_ * K_);
                #pragma unroll
                for (int k4 = 0; k4 < 4; ++k4) {
                    const float4 wv = ((const float4*)wr)[k4];
                    #pragma unroll
                    for (int jb = 0; jb < BH; ++jb) {
                        const float4 xv = *(const float4*)(xb + (size_t)jb * (IN_ * K_) + k4 * 4);
                        uh[r][jb] += wv.x*xv.x + wv.y*xv.y + wv.z*xv.z + wv.w*xv.w;
                    }
                }
            }

            // logits[b][n] = sum_d uh*os -- butterfly over the 32 d-lanes
            #pragma unroll
            for (int r = 0; r < 8; ++r) {
                const int n = r * 8 + slot;
                #pragma unroll
                for (int jb = 0; jb < BH; ++jb) {
                    float t = uh[r][jb] * os[((size_t)(b0 + jb) * N_ + n) * D_ + d];
                    #pragma unroll
                    for (int m = 1; m < 32; m <<= 1) t += __shfl_xor(t, m, 64);
                    if (d == 0) logit_s[jb][n] = t;   // lanes 0 & 32
                }
            }
            __syncthreads();
            // softmax over n: wave w <-> batch jb=w, 64 lanes = n
            {
                const float v = logit_s[w][l];
                float mx = v;
                #pragma unroll
                for (int m = 1; m < 64; m <<= 1) mx = fmaxf(mx, __shfl_xor(mx, m, 64));
                const float e = exp2f((v - mx) * SM_SCALE);
                float sum = e;
                #pragma unroll
                for (int m = 1; m < 64; m <<= 1) sum += __shfl_xor(sum, m, 64);
                logit_s[w][l] = e / sum;
            }
            __syncthreads();
            // weighted accumulate straight from registers
            #pragma unroll
            for (int r = 0; r < 8; ++r) {
                const int n = r * 8 + slot;
                #pragma unroll
                for (int jb = 0; jb < BH; ++jb)
                    s_acc[r][jb] += logit_s[jb][n] * uh[r][jb];
            }
            __syncthreads();   // protect logit_s before next i's writes
        }
    }

    const float scale = FIRST ? (1.0f / 64.0f) : 1.0f;
    if (P == NBLK) {
        float* myp = part + (size_t)virt * PCELLS;
        #pragma unroll
        for (int r = 0; r < 8; ++r) {
            const int n = r * 8 + slot;
            #pragma unroll
            for (int jb = 0; jb < BH; ++jb)
                myp[((size_t)jb * N_ + n) * D_ + d] = s_acc[r][jb] * scale;
        }
    } else {
        float* myp = part + (size_t)(blockIdx.x % P) * CELLS;
        for (int r = 0; r < 8; ++r) {
            const int n = r * 8 + slot;
            for (int jb = 0; jb < BH; ++jb)
                atomicAdd(&myp[((size_t)(b0 + jb) * N_ + n) * D_ + d], s_acc[r][jb] * scale);
        }
    }
}

// -----------------------------------------------------------------------------
// finish_kernel: s = sum of partials; out = squash(s);
// FINAL=false: os += out (next pass's logit operand); FINAL=true: write d_out.
// Compact layout: part[tile*NBG+bg][jb][n][d], b = bg*BH+jb.
// -----------------------------------------------------------------------------
template<bool FINAL>
__global__ __launch_bounds__(256)
void finish_kernel(const float* __restrict__ part, int P, int compact,
                   float* __restrict__ os, float* __restrict__ out)
{
    const int gid = blockIdx.x * 256 + threadIdx.x;   // 0..65535
    const int b   = gid >> 11;        // 0..31
    const int rem = gid & 2047;       // n*32+d
    float v = 0.f;
    if (compact) {
        const int bg = b >> 2, jb = b & 3;
        const float* p0 = part + (size_t)bg * PCELLS + (size_t)jb * (N_ * D_) + rem;
        for (int t = 0; t < NTILE; ++t) v += p0[(size_t)t * NBG * PCELLS];
    } else {
        for (int p = 0; p < P; ++p) v += part[(size_t)p * CELLS + gid];
    }
    float sq = v * v;
    #pragma unroll
    for (int m = 1; m < 32; m <<= 1) sq += __shfl_xor(sq, m, 64);  // sum over d
    const float scale = sqrtf(sq) / (1.0f + sq);
    const float o = v * scale;
    if (FINAL) out[gid] = o;
    else       os[gid] += o;
}

extern "C" void kernel_launch(void* const* d_in, const int* in_sizes, int n_in,
                              void* d_out, int out_size, void* d_ws, size_t ws_size,
                              hipStream_t stream)
{
    const float* x = (const float*)d_in[0];
    const float* W = (const float*)d_in[1];
    float* out = (float*)d_out;

    int P = NBLK;
    int compact = 1;
    float* part = (float*)d_ws;
    float* os;
    const size_t need = (size_t)NBLK * PCELLS * 4 + CELLS * 4;
    if (ws_size >= need) {
        os = part + (size_t)NBLK * PCELLS;
    } else {
        compact = 0;
        long long avail = (long long)(ws_size / 4) - (long long)CELLS;
        long long p = avail > 0 ? avail / (long long)CELLS : 1;
        P = (int)p; if (P < 1) P = 1; if (P > NBLK) P = NBLK;
        os = part + (size_t)P * CELLS;
    }

    hipMemsetAsync(os, 0, CELLS * 4, stream);

    for (int it = 0; it < 3; ++it) {
        if (!compact) hipMemsetAsync(part, 0, (size_t)P * CELLS * 4, stream);
        if (it == 0) route_kernel<true ><<<NBLK, 256, 0, stream>>>(x, W, os, part, compact ? NBLK : P);
        else         route_kernel<false><<<NBLK, 256, 0, stream>>>(x, W, os, part, compact ? NBLK : P);
        if (it < 2)  finish_kernel<false><<<CELLS / 256, 256, 0, stream>>>(part, P, compact, os, nullptr);
        else         finish_kernel<true ><<<CELLS / 256, 256, 0, stream>>>(part, P, compact, nullptr, out);
    }
}

// Round 8
// 582.561 us; speedup vs baseline: 2.3161x; 1.5774x over previous
//
#include <hip/hip_runtime.h>

#define B_    32
#define N_    64
#define IN_   2048
#define D_    32
#define K_    16
#define BH    4                    /* batches per block */
#define NBG   (B_/BH)              /* 8 batch groups */
#define ITILE 8
#define NTILE (IN_/ITILE)          /* 256 i-tiles */
#define NBLK  (NTILE*NBG)          /* 2048 blocks */
#define PCELLS ((size_t)BH*N_*D_)  /* 8192 */
#define CELLS  ((size_t)B_*N_*D_)  /* 65536 */
#define WELEMS ((size_t)N_*IN_*D_*K_)  /* 67108864 */

// softmax_e(v * INV_LOG2) == 2^((v-max) * (1/ln2)^2)
#define SM_SCALE 2.0813689810056077f

// ---- bf16 helpers (RNE) ----
__device__ __forceinline__ unsigned int rb(float f) {
    unsigned int u = __float_as_uint(f);
    return (u + 0x7fffu + ((u >> 16) & 1u)) >> 16;
}
__device__ __forceinline__ float blo(unsigned int u) {        // even k (low 16)
    return __uint_as_float(u << 16);
}
__device__ __forceinline__ float bhi(unsigned int u) {        // odd k (high 16)
    return __uint_as_float(u & 0xffff0000u);
}

// -----------------------------------------------------------------------------
// convert_kernel: W f32 -> bf16, fully coalesced stream. 8 floats/thread/iter.
// -----------------------------------------------------------------------------
__global__ __launch_bounds__(256)
void convert_kernel(const float4* __restrict__ W, uint4* __restrict__ W16)
{
    const size_t n8 = WELEMS / 8;                 // uint4 outputs
    const size_t stride = (size_t)gridDim.x * 256;
    for (size_t i = (size_t)blockIdx.x * 256 + threadIdx.x; i < n8; i += stride) {
        const float4 a = W[2 * i], b = W[2 * i + 1];
        uint4 o;
        o.x = rb(a.x) | (rb(a.y) << 16);
        o.y = rb(a.z) | (rb(a.w) << 16);
        o.z = rb(b.x) | (rb(b.y) << 16);
        o.w = rb(b.z) | (rb(b.w) << 16);
        W16[i] = o;
    }
}

// -----------------------------------------------------------------------------
// route16_kernel: one pass over bf16 W. 256 threads = (i-tile of 8, 4 batches).
// R5-R7 lessons: keep VGPR low (uh transient per r, staged in LDS as bf16x4),
// x via wave-uniform scalar loads, 3 barriers/i. bf16 W halves bytes and
// quarters L1 line-accesses vs f32 (the R5/R7 limiter).
// -----------------------------------------------------------------------------
template<bool FIRST>
__global__ __launch_bounds__(256, 1)
void route16_kernel(const float* __restrict__ x, const unsigned short* __restrict__ W16,
                    const float* __restrict__ os, float* __restrict__ part)
{
    __shared__ unsigned short uh_s[N_][D_][BH];   // 16 KB packed bf16
    __shared__ float logit_s[BH][N_];             // 1 KB

    const int tid  = threadIdx.x;   // 0..255
    const int w    = tid >> 6;      // wave 0..3
    const int l    = tid & 63;
    const int d    = l & 31;        // output dim this thread owns
    const int hi   = l >> 5;
    const int slot = w * 2 + hi;    // 0..7 -> n = r*8 + slot

    const int virt = (blockIdx.x & 7) * (NBLK / 8) + (blockIdx.x >> 3);
    const int tile = virt / NBG;
    const int bg   = virt % NBG;
    const int b0   = bg * BH;
    const int i0   = tile * ITILE;

    float s_acc[8][BH];             // 32 VGPRs
    #pragma unroll
    for (int r = 0; r < 8; ++r)
        #pragma unroll
        for (int jb = 0; jb < BH; ++jb) s_acc[r][jb] = 0.f;

    const unsigned short* wb = W16 + (((size_t)slot * IN_ + i0) * D_ + d) * K_;

    for (int ii = 0; ii < ITILE; ++ii) {
        const float* xb = x + (size_t)b0 * (IN_ * K_) + (size_t)(i0 + ii) * K_;

        #pragma unroll
        for (int r = 0; r < 8; ++r) {
            const int n = r * 8 + slot;
            const unsigned short* wr = wb + (size_t)r * (8ull * IN_ * D_ * K_)
                                          + (size_t)ii * (D_ * K_);
            const uint4 plo = *(const uint4*)(wr);       // k0..7
            const uint4 phi = *(const uint4*)(wr + 8);   // k8..15
            float wf[16];
            wf[ 0]=blo(plo.x); wf[ 1]=bhi(plo.x); wf[ 2]=blo(plo.y); wf[ 3]=bhi(plo.y);
            wf[ 4]=blo(plo.z); wf[ 5]=bhi(plo.z); wf[ 6]=blo(plo.w); wf[ 7]=bhi(plo.w);
            wf[ 8]=blo(phi.x); wf[ 9]=bhi(phi.x); wf[10]=blo(phi.y); wf[11]=bhi(phi.y);
            wf[12]=blo(phi.z); wf[13]=bhi(phi.z); wf[14]=blo(phi.w); wf[15]=bhi(phi.w);

            float uh[BH];
            #pragma unroll
            for (int jb = 0; jb < BH; ++jb) {
                // wave-uniform addresses -> scalar loads (proven R5/R7)
                const float4 x0 = *(const float4*)(xb + (size_t)jb * (IN_ * K_) + 0);
                const float4 x1 = *(const float4*)(xb + (size_t)jb * (IN_ * K_) + 4);
                const float4 x2 = *(const float4*)(xb + (size_t)jb * (IN_ * K_) + 8);
                const float4 x3 = *(const float4*)(xb + (size_t)jb * (IN_ * K_) + 12);
                uh[jb] = wf[ 0]*x0.x + wf[ 1]*x0.y + wf[ 2]*x0.z + wf[ 3]*x0.w
                       + wf[ 4]*x1.x + wf[ 5]*x1.y + wf[ 6]*x1.z + wf[ 7]*x1.w
                       + wf[ 8]*x2.x + wf[ 9]*x2.y + wf[10]*x2.z + wf[11]*x2.w
                       + wf[12]*x3.x + wf[13]*x3.y + wf[14]*x3.z + wf[15]*x3.w;
            }

            if (FIRST) {
                #pragma unroll
                for (int jb = 0; jb < BH; ++jb) s_acc[r][jb] += uh[jb];
            } else {
                // stash uh (bf16) for post-softmax accumulate: one ds_write_b64
                uint2 pk;
                pk.x = rb(uh[0]) | (rb(uh[1]) << 16);
                pk.y = rb(uh[2]) | (rb(uh[3]) << 16);
                *(uint2*)&uh_s[n][d][0] = pk;
                // logit partials: butterfly over the 32 d-lanes
                #pragma unroll
                for (int jb = 0; jb < BH; ++jb) {
                    float t = uh[jb] * os[((size_t)(b0 + jb) * N_ + n) * D_ + d];
                    #pragma unroll
                    for (int m = 1; m < 32; m <<= 1) t += __shfl_xor(t, m, 64);
                    if (d == 0) logit_s[jb][n] = t;   // lanes 0 & 32
                }
            }
        }

        if (!FIRST) {
            __syncthreads();
            // softmax over n: wave w <-> batch jb=w, 64 lanes = n
            {
                const float v = logit_s[w][l];
                float mx = v;
                #pragma unroll
                for (int m = 1; m < 64; m <<= 1) mx = fmaxf(mx, __shfl_xor(mx, m, 64));
                const float e = exp2f((v - mx) * SM_SCALE);
                float sum = e;
                #pragma unroll
                for (int m = 1; m < 64; m <<= 1) sum += __shfl_xor(sum, m, 64);
                logit_s[w][l] = e / sum;
            }
            __syncthreads();
            // weighted accumulate from LDS-staged uh
            #pragma unroll
            for (int r = 0; r < 8; ++r) {
                const int n = r * 8 + slot;
                const uint2 pk = *(const uint2*)&uh_s[n][d][0];
                s_acc[r][0] += logit_s[0][n] * blo(pk.x);
                s_acc[r][1] += logit_s[1][n] * bhi(pk.x);
                s_acc[r][2] += logit_s[2][n] * blo(pk.y);
                s_acc[r][3] += logit_s[3][n] * bhi(pk.y);
            }
            __syncthreads();   // protect uh_s/logit_s before next i's writes
        }
    }

    const float scale = FIRST ? (1.0f / 64.0f) : 1.0f;
    float* myp = part + (size_t)virt * PCELLS;
    #pragma unroll
    for (int r = 0; r < 8; ++r) {
        const int n = r * 8 + slot;
        #pragma unroll
        for (int jb = 0; jb < BH; ++jb)
            myp[((size_t)jb * N_ + n) * D_ + d] = s_acc[r][jb] * scale;
    }
}

// -----------------------------------------------------------------------------
// Legacy f32 route (R7, proven): used only if ws can't hold W16 + partials.
// -----------------------------------------------------------------------------
template<bool FIRST>
__global__ __launch_bounds__(256, 1)
void route_kernel(const float* __restrict__ x, const float* __restrict__ W,
                  const float* __restrict__ os, float* __restrict__ part, int P)
{
    __shared__ float logit_s[BH][N_];

    const int tid  = threadIdx.x;
    const int w    = tid >> 6;
    const int l    = tid & 63;
    const int d    = l & 31;
    const int hi   = l >> 5;
    const int slot = w * 2 + hi;

    const int virt = (blockIdx.x & 7) * (NBLK / 8) + (blockIdx.x >> 3);
    const int tile = virt / NBG;
    const int bg   = virt % NBG;
    const int b0   = bg * BH;
    const int i0   = tile * ITILE;

    float s_acc[8][BH];
    #pragma unroll
    for (int r = 0; r < 8; ++r)
        #pragma unroll
        for (int jb = 0; jb < BH; ++jb) s_acc[r][jb] = 0.f;

    for (int ii = 0; ii < ITILE; ++ii) {
        const int i = i0 + ii;
        const float* xb = x + (size_t)b0 * (IN_ * K_) + (size_t)i * K_;
        const float* wb = W + (((size_t)slot * IN_ + i) * D_ + d) * K_;

        float uh[8][BH];
        #pragma unroll
        for (int r = 0; r < 8; ++r)
            #pragma unroll
            for (int jb = 0; jb < BH; ++jb) uh[r][jb] = 0.f;

        #pragma unroll
        for (int r = 0; r < 8; ++r) {
            const float* wr = wb + (size_t)r * (8ull * IN_ * D_ * K_);
            #pragma unroll
            for (int k4 = 0; k4 < 4; ++k4) {
                const float4 wv = ((const float4*)wr)[k4];
                #pragma unroll
                for (int jb = 0; jb < BH; ++jb) {
                    const float4 xv = *(const float4*)(xb + (size_t)jb * (IN_ * K_) + k4 * 4);
                    uh[r][jb] += wv.x*xv.x + wv.y*xv.y + wv.z*xv.z + wv.w*xv.w;
                }
            }
        }
        if (FIRST) {
            #pragma unroll
            for (int r = 0; r < 8; ++r)
                #pragma unroll
                for (int jb = 0; jb < BH; ++jb) s_acc[r][jb] += uh[r][jb];
        } else {
            #pragma unroll
            for (int r = 0; r < 8; ++r) {
                const int n = r * 8 + slot;
                #pragma unroll
                for (int jb = 0; jb < BH; ++jb) {
                    float t = uh[r][jb] * os[((size_t)(b0 + jb) * N_ + n) * D_ + d];
                    #pragma unroll
                    for (int m = 1; m < 32; m <<= 1) t += __shfl_xor(t, m, 64);
                    if (d == 0) logit_s[jb][n] = t;
                }
            }
            __syncthreads();
            {
                const float v = logit_s[w][l];
                float mx = v;
                #pragma unroll
                for (int m = 1; m < 64; m <<= 1) mx = fmaxf(mx, __shfl_xor(mx, m, 64));
                const float e = exp2f((v - mx) * SM_SCALE);
                float sum = e;
                #pragma unroll
                for (int m = 1; m < 64; m <<= 1) sum += __shfl_xor(sum, m, 64);
                logit_s[w][l] = e / sum;
            }
            __syncthreads();
            #pragma unroll
            for (int r = 0; r < 8; ++r) {
                const int n = r * 8 + slot;
                #pragma unroll
                for (int jb = 0; jb < BH; ++jb)
                    s_acc[r][jb] += logit_s[jb][n] * uh[r][jb];
            }
            __syncthreads();
        }
    }

    const float scale = FIRST ? (1.0f / 64.0f) : 1.0f;
    if (P == NBLK) {
        float* myp = part + (size_t)virt * PCELLS;
        #pragma unroll
        for (int r = 0; r < 8; ++r) {
            const int n = r * 8 + slot;
            #pragma unroll
            for (int jb = 0; jb < BH; ++jb)
                myp[((size_t)jb * N_ + n) * D_ + d] = s_acc[r][jb] * scale;
        }
    } else {
        float* myp = part + (size_t)(blockIdx.x % P) * CELLS;
        for (int r = 0; r < 8; ++r) {
            const int n = r * 8 + slot;
            for (int jb = 0; jb < BH; ++jb)
                atomicAdd(&myp[((size_t)(b0 + jb) * N_ + n) * D_ + d], s_acc[r][jb] * scale);
        }
    }
}

// -----------------------------------------------------------------------------
// finish_kernel: s = sum of partials; out = squash(s);
// FINAL=false: os += out; FINAL=true: write d_out.
// Compact layout: part[tile*NBG+bg][jb][n][d], b = bg*BH+jb.
// -----------------------------------------------------------------------------
template<bool FINAL>
__global__ __launch_bounds__(256)
void finish_kernel(const float* __restrict__ part, int P, int compact,
                   float* __restrict__ os, float* __restrict__ out)
{
    const int gid = blockIdx.x * 256 + threadIdx.x;
    const int b   = gid >> 11;
    const int rem = gid & 2047;
    float v = 0.f;
    if (compact) {
        const int bg = b >> 2, jb = b & 3;
        const float* p0 = part + (size_t)bg * PCELLS + (size_t)jb * (N_ * D_) + rem;
        for (int t = 0; t < NTILE; ++t) v += p0[(size_t)t * NBG * PCELLS];
    } else {
        for (int p = 0; p < P; ++p) v += part[(size_t)p * CELLS + gid];
    }
    float sq = v * v;
    #pragma unroll
    for (int m = 1; m < 32; m <<= 1) sq += __shfl_xor(sq, m, 64);
    const float scale = sqrtf(sq) / (1.0f + sq);
    const float o = v * scale;
    if (FINAL) out[gid] = o;
    else       os[gid] += o;
}

extern "C" void kernel_launch(void* const* d_in, const int* in_sizes, int n_in,
                              void* d_out, int out_size, void* d_ws, size_t ws_size,
                              hipStream_t stream)
{
    const float* x = (const float*)d_in[0];
    const float* W = (const float*)d_in[1];
    float* out = (float*)d_out;

    const size_t w16_bytes  = WELEMS * 2;                  // 128 MB
    const size_t part_bytes = (size_t)NBLK * PCELLS * 4;   // 64 MB
    const size_t need16     = w16_bytes + part_bytes + CELLS * 4;

    if (ws_size >= need16) {
        unsigned short* W16 = (unsigned short*)d_ws;
        float* part = (float*)((char*)d_ws + w16_bytes);
        float* os   = part + (size_t)NBLK * PCELLS;

        hipMemsetAsync(os, 0, CELLS * 4, stream);
        convert_kernel<<<2048, 256, 0, stream>>>((const float4*)W, (uint4*)d_ws);

        for (int it = 0; it < 3; ++it) {
            if (it == 0) route16_kernel<true ><<<NBLK, 256, 0, stream>>>(x, W16, os, part);
            else         route16_kernel<false><<<NBLK, 256, 0, stream>>>(x, W16, os, part);
            if (it < 2)  finish_kernel<false><<<CELLS / 256, 256, 0, stream>>>(part, NBLK, 1, os, nullptr);
            else         finish_kernel<true ><<<CELLS / 256, 256, 0, stream>>>(part, NBLK, 1, nullptr, out);
        }
        return;
    }

    // ---- legacy f32 fallback (R7) ----
    int P = NBLK;
    int compact = 1;
    float* part = (float*)d_ws;
    float* os;
    const size_t need = part_bytes + CELLS * 4;
    if (ws_size >= need) {
        os = part + (size_t)NBLK * PCELLS;
    } else {
        compact = 0;
        long long avail = (long long)(ws_size / 4) - (long long)CELLS;
        long long p = avail > 0 ? avail / (long long)CELLS : 1;
        P = (int)p; if (P < 1) P = 1; if (P > NBLK) P = NBLK;
        os = part + (size_t)P * CELLS;
    }

    hipMemsetAsync(os, 0, CELLS * 4, stream);

    for (int it = 0; it < 3; ++it) {
        if (!compact) hipMemsetAsync(part, 0, (size_t)P * CELLS * 4, stream);
        if (it == 0) route_kernel<true ><<<NBLK, 256, 0, stream>>>(x, W, os, part, compact ? NBLK : P);
        else         route_kernel<false><<<NBLK, 256, 0, stream>>>(x, W, os, part, compact ? NBLK : P);
        if (it < 2)  finish_kernel<false><<<CELLS / 256, 256, 0, stream>>>(part, P, compact, os, nullptr);
        else         finish_kernel<true ><<<CELLS / 256, 256, 0, stream>>>(part, P, compact, nullptr, out);
    }
}